// Round 3
// baseline (43.921 us; speedup 1.0000x reference)
//
#include <hip/hip_runtime.h>

// RandomResizedCropPair: bilinear crop-resize (image) + nearest crop-resize (mask)
// image: [32,3,512,512] f32, mask: [32,1,512,512] f32
// crop_size/top/left: [32] i32
// out: img [32,3,384,384] f32 ++ msk [32,1,384,384] f32
//
// R2: 4 px/thread, nontemporal 16B stores via clang ext_vector_type
// (__builtin_nontemporal_store rejects HIP_vector_type float4).

constexpr int OUT = 384;
constexpr int H = 512;
constexpr int W = 512;
constexpr int B = 32;
constexpr int C = 3;
constexpr int JQ = OUT / 4;  // 96 float4 groups per row

typedef float f32x4 __attribute__((ext_vector_type(4)));

__global__ __launch_bounds__(256) void rrc_pair_kernel(
    const float* __restrict__ image,
    const float* __restrict__ mask,
    const int* __restrict__ crop_size,
    const int* __restrict__ top,
    const int* __restrict__ left,
    float* __restrict__ img_out,
    float* __restrict__ msk_out)
{
    int tid = blockIdx.x * blockDim.x + threadIdx.x;
    if (tid >= B * OUT * JQ) return;
    int jq = tid % JQ;
    int rest = tid / JQ;
    int i = rest % OUT;
    int b = rest / OUT;

    const int cs = crop_size[b];
    const int t  = top[b];
    const int l  = left[b];
    const float csf = (float)cs;
    const float s   = csf / (float)OUT;   // match reference: csf/SIZE first

    // --- bilinear y (shared by the 4 pixels) ---
    float cy = ((float)i + 0.5f) * s - 0.5f;
    cy = fminf(fmaxf(cy, 0.0f), csf - 1.0f);
    int   iy0 = (int)floorf(cy);
    int   iy1 = min(iy0 + 1, cs - 1);
    float wy  = cy - (float)iy0;
    const int y0 = iy0 + t, y1 = iy1 + t;

    // --- bilinear x for 4 consecutive output columns ---
    int   x0[4], x1[4];
    float wxa[4];
    #pragma unroll
    for (int k = 0; k < 4; ++k) {
        int jj = jq * 4 + k;
        float cx = ((float)jj + 0.5f) * s - 0.5f;
        cx = fminf(fmaxf(cx, 0.0f), csf - 1.0f);
        int ix0 = (int)floorf(cx);
        int ix1 = min(ix0 + 1, cs - 1);
        wxa[k] = cx - (float)ix0;
        x0[k] = ix0 + l;
        x1[k] = ix1 + l;
    }

    const float* imgb = image + (size_t)b * C * H * W;
    const size_t row_off = (size_t)i * OUT + (size_t)jq * 4;

    #pragma unroll
    for (int c = 0; c < C; ++c) {
        const float* p0 = imgb + (size_t)c * H * W + (size_t)y0 * W;
        const float* p1 = imgb + (size_t)c * H * W + (size_t)y1 * W;
        f32x4 o;
        #pragma unroll
        for (int k = 0; k < 4; ++k) {
            float wx = wxa[k];
            float v00 = p0[x0[k]];
            float v01 = p0[x1[k]];
            float v10 = p1[x0[k]];
            float v11 = p1[x1[k]];
            float top_v = v00 * (1.0f - wx) + v01 * wx;
            float bot_v = v10 * (1.0f - wx) + v11 * wx;
            o[k] = top_v * (1.0f - wy) + bot_v * wy;
        }
        float* dst = img_out + (size_t)b * C * OUT * OUT + (size_t)c * OUT * OUT + row_off;
        __builtin_nontemporal_store(o, (f32x4*)dst);
    }

    // --- nearest mask: src = floor(dst * cs / OUT), exact integer math ---
    int my = (i * cs) / OUT; my = min(my, cs - 1);
    const float* mrow = mask + ((size_t)b * H + (size_t)(my + t)) * W;
    f32x4 m;
    #pragma unroll
    for (int k = 0; k < 4; ++k) {
        int jj = jq * 4 + k;
        int mx = (jj * cs) / OUT; mx = min(mx, cs - 1);
        m[k] = mrow[mx + l];
    }
    float* mdst = msk_out + (size_t)b * OUT * OUT + row_off;
    __builtin_nontemporal_store(m, (f32x4*)mdst);
}

extern "C" void kernel_launch(void* const* d_in, const int* in_sizes, int n_in,
                              void* d_out, int out_size, void* d_ws, size_t ws_size,
                              hipStream_t stream) {
    const float* image = (const float*)d_in[0];
    const float* mask  = (const float*)d_in[1];
    const int* cs      = (const int*)d_in[2];
    const int* top     = (const int*)d_in[3];
    const int* left    = (const int*)d_in[4];

    float* img_out = (float*)d_out;
    float* msk_out = img_out + (size_t)B * C * OUT * OUT;

    const int total = B * OUT * JQ;
    dim3 block(256);
    dim3 grid((total + 255) / 256);
    hipLaunchKernelGGL(rrc_pair_kernel, grid, block, 0, stream,
                       image, mask, cs, top, left, img_out, msk_out);
}

// Round 4
// 41.267 us; speedup vs baseline: 1.0643x; 1.0643x over previous
//
#include <hip/hip_runtime.h>

// RandomResizedCropPair: bilinear crop-resize (image) + nearest crop-resize (mask)
// image: [32,3,512,512] f32, mask: [32,1,512,512] f32
// crop_size/top/left: [32] i32
// out: img [32,3,384,384] f32 ++ msk [32,1,384,384] f32
//
// R3: 1 px/thread (max waves for latency hiding) + nontemporal scalar stores
// (R2 showed NT stores cut FETCH 86->64 MB by not evicting inputs from L2/L3,
// but 4px/thread halved occupancy and lost the win).

constexpr int OUT = 384;
constexpr int H = 512;
constexpr int W = 512;
constexpr int B = 32;
constexpr int C = 3;
constexpr int BLOCKS_PER_B = (OUT * OUT) / 256;  // 576, exact

__global__ __launch_bounds__(256) void rrc_pair_kernel(
    const float* __restrict__ image,
    const float* __restrict__ mask,
    const int* __restrict__ crop_size,
    const int* __restrict__ top,
    const int* __restrict__ left,
    float* __restrict__ img_out,
    float* __restrict__ msk_out)
{
    // b derived from blockIdx only -> cs/t/l are wave-uniform scalar loads
    const int b   = blockIdx.x / BLOCKS_PER_B;
    const int pix = (blockIdx.x % BLOCKS_PER_B) * 256 + threadIdx.x;
    const int j = pix % OUT;
    const int i = pix / OUT;

    const int cs = crop_size[b];
    const int t  = top[b];
    const int l  = left[b];
    const float csf = (float)cs;
    const float s   = csf / (float)OUT;   // match reference: csf/SIZE first

    // --- bilinear y ---
    float cy = ((float)i + 0.5f) * s - 0.5f;
    cy = fminf(fmaxf(cy, 0.0f), csf - 1.0f);
    int   iy0 = (int)floorf(cy);
    int   iy1 = min(iy0 + 1, cs - 1);
    float wy  = cy - (float)iy0;

    // --- bilinear x ---
    float cx = ((float)j + 0.5f) * s - 0.5f;
    cx = fminf(fmaxf(cx, 0.0f), csf - 1.0f);
    int   ix0 = (int)floorf(cx);
    int   ix1 = min(ix0 + 1, cs - 1);
    float wx  = cx - (float)ix0;

    const int y0 = iy0 + t, y1 = iy1 + t;
    const int x0 = ix0 + l, x1 = ix1 + l;

    const float w00 = (1.0f - wy) * (1.0f - wx);
    const float w01 = (1.0f - wy) * wx;
    const float w10 = wy * (1.0f - wx);
    const float w11 = wy * wx;

    const float* imgb = image + (size_t)b * C * H * W;
    const size_t o_base = (size_t)b * C * OUT * OUT + (size_t)i * OUT + (size_t)j;

    #pragma unroll
    for (int c = 0; c < C; ++c) {
        const float* p = imgb + (size_t)c * H * W;
        float v00 = p[(size_t)y0 * W + x0];
        float v01 = p[(size_t)y0 * W + x1];
        float v10 = p[(size_t)y1 * W + x0];
        float v11 = p[(size_t)y1 * W + x1];
        float r = v00 * w00 + v01 * w01 + v10 * w10 + v11 * w11;
        __builtin_nontemporal_store(r, img_out + o_base + (size_t)c * OUT * OUT);
    }

    // --- nearest mask: src = floor(dst * cs / OUT), exact integer math ---
    int my = (i * cs) / OUT; my = min(my, cs - 1);
    int mx = (j * cs) / OUT; mx = min(mx, cs - 1);
    float mval = mask[((size_t)b * H + (size_t)(my + t)) * W + (mx + l)];
    __builtin_nontemporal_store(mval, msk_out + ((size_t)b * OUT + i) * OUT + j);
}

extern "C" void kernel_launch(void* const* d_in, const int* in_sizes, int n_in,
                              void* d_out, int out_size, void* d_ws, size_t ws_size,
                              hipStream_t stream) {
    const float* image = (const float*)d_in[0];
    const float* mask  = (const float*)d_in[1];
    const int* cs      = (const int*)d_in[2];
    const int* top     = (const int*)d_in[3];
    const int* left    = (const int*)d_in[4];

    float* img_out = (float*)d_out;
    float* msk_out = img_out + (size_t)B * C * OUT * OUT;

    dim3 block(256);
    dim3 grid(B * BLOCKS_PER_B);
    hipLaunchKernelGGL(rrc_pair_kernel, grid, block, 0, stream,
                       image, mask, cs, top, left, img_out, msk_out);
}

// Round 5
// 37.409 us; speedup vs baseline: 1.1741x; 1.1031x over previous
//
#include <hip/hip_runtime.h>

// RandomResizedCropPair: bilinear crop-resize (image) + nearest crop-resize (mask)
// image: [32,3,512,512] f32, mask: [32,1,512,512] f32
// out: img [32,3,384,384] f32 ++ msk [32,1,384,384] f32
//
// R4: persistent grid — 2048 blocks x 9 iters of 256 px, contiguous range per
// block (b/cs/t/l block-uniform), XCD-chunked swizzle (each XCD owns 4 images
// so adjacent-row input reuse is intra-L2). NT stores kept from R3.

constexpr int OUT = 384;
constexpr int H = 512;
constexpr int W = 512;
constexpr int B = 32;
constexpr int C = 3;
constexpr int PIX_PER_IMG = OUT * OUT;          // 147456
constexpr int NBLK = 2048;                       // 8 per CU
constexpr int ITERS = (B * PIX_PER_IMG) / (NBLK * 256);  // 9, exact
constexpr int PIX_PER_BLK = ITERS * 256;         // 2304; 147456 % 2304 == 0
constexpr int NXCD = 8;

__global__ __launch_bounds__(256) void rrc_pair_kernel(
    const float* __restrict__ image,
    const float* __restrict__ mask,
    const int* __restrict__ crop_size,
    const int* __restrict__ top,
    const int* __restrict__ left,
    float* __restrict__ img_out,
    float* __restrict__ msk_out)
{
    // Bijective XCD-chunk swizzle: hw blocks round-robin across 8 XCDs, so
    // XCD x gets logical range [x*256, (x+1)*256) -> images [4x, 4x+4).
    const int hw = blockIdx.x;
    const int logical = (hw % NXCD) * (NBLK / NXCD) + hw / NXCD;

    const int blk_base = logical * PIX_PER_BLK;
    const int b = blk_base / PIX_PER_IMG;        // block-uniform (no straddle)

    const int cs = crop_size[b];
    const int t  = top[b];
    const int l  = left[b];
    const float csf = (float)cs;
    const float s   = csf / (float)OUT;          // match reference: csf/SIZE first

    const float* imgb = image + (size_t)b * C * H * W;
    const float* mskb = mask + (size_t)b * H * W;

    #pragma unroll
    for (int it = 0; it < ITERS; ++it) {
        const int pix = blk_base + it * 256 + (int)threadIdx.x;
        const int r = pix - b * PIX_PER_IMG;     // pixel within image
        const int i = r / OUT;
        const int j = r - i * OUT;

        // --- bilinear y ---
        float cy = ((float)i + 0.5f) * s - 0.5f;
        cy = fminf(fmaxf(cy, 0.0f), csf - 1.0f);
        int   iy0 = (int)floorf(cy);
        int   iy1 = min(iy0 + 1, cs - 1);
        float wy  = cy - (float)iy0;

        // --- bilinear x ---
        float cx = ((float)j + 0.5f) * s - 0.5f;
        cx = fminf(fmaxf(cx, 0.0f), csf - 1.0f);
        int   ix0 = (int)floorf(cx);
        int   ix1 = min(ix0 + 1, cs - 1);
        float wx  = cx - (float)ix0;

        const int y0 = iy0 + t, y1 = iy1 + t;
        const int x0 = ix0 + l, x1 = ix1 + l;

        const float w00 = (1.0f - wy) * (1.0f - wx);
        const float w01 = (1.0f - wy) * wx;
        const float w10 = wy * (1.0f - wx);
        const float w11 = wy * wx;

        const size_t o_base = (size_t)b * C * PIX_PER_IMG + (size_t)r;

        #pragma unroll
        for (int c = 0; c < C; ++c) {
            const float* p = imgb + (size_t)c * H * W;
            float v00 = p[(size_t)y0 * W + x0];
            float v01 = p[(size_t)y0 * W + x1];
            float v10 = p[(size_t)y1 * W + x0];
            float v11 = p[(size_t)y1 * W + x1];
            float rr = v00 * w00 + v01 * w01 + v10 * w10 + v11 * w11;
            __builtin_nontemporal_store(rr, img_out + o_base + (size_t)c * PIX_PER_IMG);
        }

        // --- nearest mask: src = floor(dst * cs / OUT), exact integer math ---
        int my = (i * cs) / OUT; my = min(my, cs - 1);
        int mx = (j * cs) / OUT; mx = min(mx, cs - 1);
        float mval = mskb[(size_t)(my + t) * W + (mx + l)];
        __builtin_nontemporal_store(mval, msk_out + (size_t)b * PIX_PER_IMG + (size_t)r);
    }
}

extern "C" void kernel_launch(void* const* d_in, const int* in_sizes, int n_in,
                              void* d_out, int out_size, void* d_ws, size_t ws_size,
                              hipStream_t stream) {
    const float* image = (const float*)d_in[0];
    const float* mask  = (const float*)d_in[1];
    const int* cs      = (const int*)d_in[2];
    const int* top     = (const int*)d_in[3];
    const int* left    = (const int*)d_in[4];

    float* img_out = (float*)d_out;
    float* msk_out = img_out + (size_t)B * C * PIX_PER_IMG;

    dim3 block(256);
    dim3 grid(NBLK);
    hipLaunchKernelGGL(rrc_pair_kernel, grid, block, 0, stream,
                       image, mask, cs, top, left, img_out, msk_out);
}

// Round 6
// 36.420 us; speedup vs baseline: 1.2060x; 1.0272x over previous
//
#include <hip/hip_runtime.h>

// RandomResizedCropPair: bilinear crop-resize (image) + nearest crop-resize (mask)
// image: [32,3,512,512] f32, mask: [32,1,512,512] f32
// out: img [32,3,384,384] f32 ++ msk [32,1,384,384] f32
//
// R5: R3's 1-px/thread grid (18432 blocks, VGPR ~20, 75% occupancy) +
// R4's XCD-chunked swizzle (each XCD owns 4 whole images -> input-row reuse
// between adjacent output rows is intra-L2; FETCH 86->57 MB in R4).
// NT stores keep outputs from evicting inputs.

constexpr int OUT = 384;
constexpr int H = 512;
constexpr int W = 512;
constexpr int B = 32;
constexpr int C = 3;
constexpr int BLOCKS_PER_B = (OUT * OUT) / 256;       // 576
constexpr int NBLK = B * BLOCKS_PER_B;                // 18432
constexpr int BLOCKS_PER_XCD = NBLK / 8;              // 2304 = 4 images

__global__ __launch_bounds__(256) void rrc_pair_kernel(
    const float* __restrict__ image,
    const float* __restrict__ mask,
    const int* __restrict__ crop_size,
    const int* __restrict__ top,
    const int* __restrict__ left,
    float* __restrict__ img_out,
    float* __restrict__ msk_out)
{
    // Bijective XCD swizzle: hw%8 = XCD (round-robin dispatch), so XCD x gets
    // logical blocks [x*2304, (x+1)*2304) = images [4x, 4x+4).
    const int hw = blockIdx.x;
    const int logical = (hw & 7) * BLOCKS_PER_XCD + (hw >> 3);

    const int b   = logical / BLOCKS_PER_B;           // block-uniform
    const int pix = (logical % BLOCKS_PER_B) * 256 + (int)threadIdx.x;
    const int j = pix % OUT;
    const int i = pix / OUT;

    const int cs = crop_size[b];
    const int t  = top[b];
    const int l  = left[b];
    const float csf = (float)cs;
    const float s   = csf / (float)OUT;               // match reference order

    // --- bilinear y ---
    float cy = ((float)i + 0.5f) * s - 0.5f;
    cy = fminf(fmaxf(cy, 0.0f), csf - 1.0f);
    int   iy0 = (int)floorf(cy);
    int   iy1 = min(iy0 + 1, cs - 1);
    float wy  = cy - (float)iy0;

    // --- bilinear x ---
    float cx = ((float)j + 0.5f) * s - 0.5f;
    cx = fminf(fmaxf(cx, 0.0f), csf - 1.0f);
    int   ix0 = (int)floorf(cx);
    int   ix1 = min(ix0 + 1, cs - 1);
    float wx  = cx - (float)ix0;

    const int y0 = iy0 + t, y1 = iy1 + t;
    const int x0 = ix0 + l, x1 = ix1 + l;

    const float w00 = (1.0f - wy) * (1.0f - wx);
    const float w01 = (1.0f - wy) * wx;
    const float w10 = wy * (1.0f - wx);
    const float w11 = wy * wx;

    const float* imgb = image + (size_t)b * C * H * W;
    const size_t o_base = (size_t)b * C * OUT * OUT + (size_t)i * OUT + (size_t)j;

    #pragma unroll
    for (int c = 0; c < C; ++c) {
        const float* p = imgb + (size_t)c * H * W;
        float v00 = p[(size_t)y0 * W + x0];
        float v01 = p[(size_t)y0 * W + x1];
        float v10 = p[(size_t)y1 * W + x0];
        float v11 = p[(size_t)y1 * W + x1];
        float r = v00 * w00 + v01 * w01 + v10 * w10 + v11 * w11;
        __builtin_nontemporal_store(r, img_out + o_base + (size_t)c * OUT * OUT);
    }

    // --- nearest mask: src = floor(dst * cs / OUT), exact integer math ---
    int my = (i * cs) / OUT; my = min(my, cs - 1);
    int mx = (j * cs) / OUT; mx = min(mx, cs - 1);
    float mval = mask[((size_t)b * H + (size_t)(my + t)) * W + (mx + l)];
    __builtin_nontemporal_store(mval, msk_out + ((size_t)b * OUT + i) * OUT + j);
}

extern "C" void kernel_launch(void* const* d_in, const int* in_sizes, int n_in,
                              void* d_out, int out_size, void* d_ws, size_t ws_size,
                              hipStream_t stream) {
    const float* image = (const float*)d_in[0];
    const float* mask  = (const float*)d_in[1];
    const int* cs      = (const int*)d_in[2];
    const int* top     = (const int*)d_in[3];
    const int* left    = (const int*)d_in[4];

    float* img_out = (float*)d_out;
    float* msk_out = img_out + (size_t)B * C * OUT * OUT;

    dim3 block(256);
    dim3 grid(NBLK);
    hipLaunchKernelGGL(rrc_pair_kernel, grid, block, 0, stream,
                       image, mask, cs, top, left, img_out, msk_out);
}

// Round 7
// 33.091 us; speedup vs baseline: 1.3273x; 1.1006x over previous
//
#include <hip/hip_runtime.h>

// RandomResizedCropPair: bilinear crop-resize (image) + nearest crop-resize (mask)
// image: [32,3,512,512] f32, mask: [32,1,512,512] f32
// out: img [32,3,384,384] f32 ++ msk [32,1,384,384] f32
//
// R6: one block per output row (b,i). y0/y1 are block-uniform, so stage the
// 6 needed input rows (2 y-rows x 3 ch, full 512 width, 12 KB LDS) with
// coalesced float4 loads, then do the 12 bilinear taps as LDS gathers.
// VMEM/thread: 17 -> 7. XCD swizzle + NT stores kept from R5.

constexpr int OUT = 384;
constexpr int H = 512;
constexpr int W = 512;
constexpr int B = 32;
constexpr int C = 3;
constexpr int NBLK = B * OUT;          // 12288 blocks, one per (b, i)
constexpr int BPX  = NBLK / 8;         // 1536 blocks per XCD = 4 images

typedef float f32x4 __attribute__((ext_vector_type(4)));

__global__ __launch_bounds__(384) void rrc_pair_kernel(
    const float* __restrict__ image,
    const float* __restrict__ mask,
    const int* __restrict__ crop_size,
    const int* __restrict__ top,
    const int* __restrict__ left,
    float* __restrict__ img_out,
    float* __restrict__ msk_out)
{
    __shared__ float lds[2 * C][W];    // [c*2+h][512], h: 0=y0 row, 1=y1 row

    // Bijective XCD swizzle: hw%8 = XCD, each XCD owns 4 whole images.
    const int hw = blockIdx.x;
    const int logical = (hw & 7) * BPX + (hw >> 3);
    const int b = logical / OUT;       // block-uniform
    const int i = logical % OUT;       // output row, block-uniform
    const int tid = (int)threadIdx.x;  // = output column j

    const int cs = crop_size[b];
    const int t  = top[b];
    const int l  = left[b];
    const float csf = (float)cs;
    const float s   = csf / (float)OUT;        // match reference: csf/SIZE first

    // --- bilinear y (block-uniform) ---
    float cy = ((float)i + 0.5f) * s - 0.5f;
    cy = fminf(fmaxf(cy, 0.0f), csf - 1.0f);
    int   iy0 = (int)floorf(cy);
    int   iy1 = min(iy0 + 1, cs - 1);
    float wy  = cy - (float)iy0;
    const int y0 = iy0 + t, y1 = iy1 + t;

    const float* imgb = image + (size_t)b * C * H * W;

    // --- stage 6 input rows into LDS: 3072 floats, 8 per thread, float4 x2 ---
    {
        const int base = tid * 8;
        const int r    = base >> 9;            // row slot 0..5
        const int col  = base & 511;
        const int c    = r >> 1;
        const int y    = (r & 1) ? y1 : y0;
        const float* src = imgb + ((size_t)c * H + (size_t)y) * W + col;
        f32x4 a0 = *(const f32x4*)src;
        f32x4 a1 = *(const f32x4*)(src + 4);
        *(f32x4*)&lds[r][col]     = a0;
        *(f32x4*)&lds[r][col + 4] = a1;
    }

    // --- mask gather issued before barrier to overlap staging latency ---
    int my = (i * cs) / OUT;   my = min(my, cs - 1);
    int mx = (tid * cs) / OUT; mx = min(mx, cs - 1);
    const float mval = mask[((size_t)b * H + (size_t)(my + t)) * W + (mx + l)];

    __syncthreads();

    // --- bilinear x for this thread's pixel ---
    const int j = tid;
    float cx = ((float)j + 0.5f) * s - 0.5f;
    cx = fminf(fmaxf(cx, 0.0f), csf - 1.0f);
    int   ix0 = (int)floorf(cx);
    int   ix1 = min(ix0 + 1, cs - 1);
    float wx  = cx - (float)ix0;
    const int x0 = ix0 + l, x1 = ix1 + l;      // indices into the full row

    const float w00 = (1.0f - wy) * (1.0f - wx);
    const float w01 = (1.0f - wy) * wx;
    const float w10 = wy * (1.0f - wx);
    const float w11 = wy * wx;

    const size_t o_base = (size_t)b * C * OUT * OUT + (size_t)i * OUT + (size_t)j;

    #pragma unroll
    for (int c = 0; c < C; ++c) {
        float v00 = lds[c * 2][x0];
        float v01 = lds[c * 2][x1];
        float v10 = lds[c * 2 + 1][x0];
        float v11 = lds[c * 2 + 1][x1];
        float r = v00 * w00 + v01 * w01 + v10 * w10 + v11 * w11;
        __builtin_nontemporal_store(r, img_out + o_base + (size_t)c * OUT * OUT);
    }

    __builtin_nontemporal_store(mval,
        msk_out + (size_t)b * OUT * OUT + (size_t)i * OUT + (size_t)j);
}

extern "C" void kernel_launch(void* const* d_in, const int* in_sizes, int n_in,
                              void* d_out, int out_size, void* d_ws, size_t ws_size,
                              hipStream_t stream) {
    const float* image = (const float*)d_in[0];
    const float* mask  = (const float*)d_in[1];
    const int* cs      = (const int*)d_in[2];
    const int* top     = (const int*)d_in[3];
    const int* left    = (const int*)d_in[4];

    float* img_out = (float*)d_out;
    float* msk_out = img_out + (size_t)B * C * OUT * OUT;

    dim3 block(384);
    dim3 grid(NBLK);
    hipLaunchKernelGGL(rrc_pair_kernel, grid, block, 0, stream,
                       image, mask, cs, top, left, img_out, msk_out);
}

// Round 8
// 32.988 us; speedup vs baseline: 1.3314x; 1.0031x over previous
//
#include <hip/hip_runtime.h>

// RandomResizedCropPair: bilinear crop-resize (image) + nearest crop-resize (mask)
// image: [32,3,512,512] f32, mask: [32,1,512,512] f32
// out: img [32,3,384,384] f32 ++ msk [32,1,384,384] f32
//
// R7: 4 output rows per block (384 thr, thread = column j, 4 px at same j).
// The 4 rows' taps span <= 6 input rows/channel (s <= 511/384), so stage
// 18 rows (6 x 3ch, stride 520 dw, 37.4 KB -> 4 blocks/CU). Amortizes
// staging (6 -> 4.5 rows per output row), barrier (/4), x-math (x1 = x0+1
// with a guard word at col 512; clip edge has wx == 0 exactly so the
// guarded tap contributes 0). XCD swizzle + NT stores kept.

constexpr int OUT = 384;
constexpr int H = 512;
constexpr int W = 512;
constexpr int B = 32;
constexpr int C = 3;
constexpr int RPB = 4;                 // output rows per block
constexpr int GPB = OUT / RPB;         // 96 row-groups per image
constexpr int NBLK = B * GPB;          // 3072
constexpr int BPX  = NBLK / 8;         // 384 blocks/XCD = 4 whole images
constexpr int NSLOT = 6;               // input-row slots per channel
constexpr int LROWS = C * NSLOT;       // 18
constexpr int LDSW  = 520;             // dword row stride (512 data + guard + pad)

typedef float f32x4 __attribute__((ext_vector_type(4)));

__global__ __launch_bounds__(OUT) void rrc_pair_kernel(
    const float* __restrict__ image,
    const float* __restrict__ mask,
    const int* __restrict__ crop_size,
    const int* __restrict__ top,
    const int* __restrict__ left,
    float* __restrict__ img_out,
    float* __restrict__ msk_out)
{
    __shared__ float lds[LROWS * LDSW];

    // Bijective XCD swizzle: hw%8 = XCD, each XCD owns 4 whole images.
    const int hw = blockIdx.x;
    const int logical = (hw & 7) * BPX + (hw >> 3);
    const int b  = logical / GPB;                 // block-uniform
    const int i0 = (logical % GPB) * RPB;         // first output row
    const int tid = (int)threadIdx.x;             // = output column j

    const int cs = crop_size[b];
    const int t  = top[b];
    const int l  = left[b];
    const float csf = (float)cs;
    const float s   = csf / (float)OUT;           // match reference order

    // Block-uniform base input row (iy0 of the group's first output row).
    float cy0 = ((float)i0 + 0.5f) * s - 0.5f;
    cy0 = fminf(fmaxf(cy0, 0.0f), csf - 1.0f);
    const int base_y = (int)floorf(cy0);

    const float* imgb = image + (size_t)b * C * H * W;

    // --- stage 18 input rows (full 512 width) + guard word per row ---
    // 18*512 = 9216 floats = 2304 f32x4 chunks = 384 threads x 6.
    #pragma unroll
    for (int k = 0; k < 6; ++k) {
        const int q   = tid + k * OUT;            // chunk id 0..2303
        const int r   = q >> 7;                   // LDS row 0..17
        const int col = (q & 127) * 4;
        const int c    = r / NSLOT;
        const int slot = r % NSLOT;
        const int y = min(t + base_y + slot, H - 1);
        const float* src = imgb + ((size_t)c * H + (size_t)y) * W + col;
        f32x4 v = *(const f32x4*)src;
        *(f32x4*)&lds[r * LDSW + col] = v;
        if ((q & 127) == 127) lds[r * LDSW + 512] = v[3];  // guard = copy of col 511
    }

    // --- x geometry, once per thread ---
    float cx = ((float)tid + 0.5f) * s - 0.5f;
    cx = fminf(fmaxf(cx, 0.0f), csf - 1.0f);
    const int   ix0 = (int)floorf(cx);
    const float wx  = cx - (float)ix0;
    const int   x0  = ix0 + l;                    // read cols x0, x0+1 (guarded)

    const int mx = min((tid * cs) / OUT, cs - 1) + l;

    // --- mask gathers before the barrier (overlap staging latency) ---
    float mval[RPB];
    #pragma unroll
    for (int r4 = 0; r4 < RPB; ++r4) {
        const int i = i0 + r4;
        int my = min((i * cs) / OUT, cs - 1);
        mval[r4] = mask[((size_t)b * H + (size_t)(my + t)) * W + mx];
    }

    __syncthreads();

    #pragma unroll
    for (int r4 = 0; r4 < RPB; ++r4) {
        const int i = i0 + r4;
        float cy = ((float)i + 0.5f) * s - 0.5f;
        cy = fminf(fmaxf(cy, 0.0f), csf - 1.0f);
        int   iy0 = (int)floorf(cy);
        int   iy1 = min(iy0 + 1, cs - 1);
        float wy  = cy - (float)iy0;
        const int slot0 = iy0 - base_y;                       // 0..4
        const int slot1 = min(iy1 - base_y, NSLOT - 1);       // <= 5 (clamp = safety)

        const float w00 = (1.0f - wy) * (1.0f - wx);
        const float w01 = (1.0f - wy) * wx;
        const float w10 = wy * (1.0f - wx);
        const float w11 = wy * wx;

        const size_t o_base = (size_t)b * C * OUT * OUT + (size_t)i * OUT + (size_t)tid;

        #pragma unroll
        for (int c = 0; c < C; ++c) {
            const float* rA = &lds[(c * NSLOT + slot0) * LDSW + x0];
            const float* rB = &lds[(c * NSLOT + slot1) * LDSW + x0];
            float v00 = rA[0], v01 = rA[1];   // ds_read2_b32 pair
            float v10 = rB[0], v11 = rB[1];
            float rr = v00 * w00 + v01 * w01 + v10 * w10 + v11 * w11;
            __builtin_nontemporal_store(rr, img_out + o_base + (size_t)c * OUT * OUT);
        }
        __builtin_nontemporal_store(mval[r4],
            msk_out + (size_t)b * OUT * OUT + (size_t)i * OUT + (size_t)tid);
    }
}

extern "C" void kernel_launch(void* const* d_in, const int* in_sizes, int n_in,
                              void* d_out, int out_size, void* d_ws, size_t ws_size,
                              hipStream_t stream) {
    const float* image = (const float*)d_in[0];
    const float* mask  = (const float*)d_in[1];
    const int* cs      = (const int*)d_in[2];
    const int* top     = (const int*)d_in[3];
    const int* left    = (const int*)d_in[4];

    float* img_out = (float*)d_out;
    float* msk_out = img_out + (size_t)B * C * OUT * OUT;

    dim3 block(OUT);
    dim3 grid(NBLK);
    hipLaunchKernelGGL(rrc_pair_kernel, grid, block, 0, stream,
                       image, mask, cs, top, left, img_out, msk_out);
}